// Round 4
// baseline (3821.731 us; speedup 1.0000x reference)
//
#include <hip/hip_runtime.h>
#include <hip/hip_bf16.h>
#include <math.h>

#define BATCH 128
#define NCH 19
#define TLEN 1000
#define NNODES (BATCH * NCH)

__device__ __forceinline__ float eluf(float x) { return x > 0.f ? x : expm1f(x); }
__device__ __forceinline__ float geluf(float x) { return 0.5f * x * (1.f + erff(x * 0.70710678118654752f)); }
__device__ __forceinline__ float sigf(float x) { return 1.f / (1.f + expf(-x)); }
__device__ __forceinline__ float lrelu(float x) { return x > 0.f ? x : 0.2f * x; }

// ---------------------------------------------------------------------------
// K1: full EEGNet frontend for one batch element, all intermediates in LDS.
//   conv1(1x25,p12)+bn1 + depthwise(sum C)+bn2+elu (virtual y2)
//   SE squeeze/excite; avgpool4 -> y4pre (LDS); sep conv+bn3+elu+mean -> yv
// grid: B blocks, 256 thr
// ---------------------------------------------------------------------------
__global__ __launch_bounds__(256) void k_front(
    const float* __restrict__ x, const float* __restrict__ w1,
    const float* __restrict__ bn1g, const float* __restrict__ bn1b,
    const float* __restrict__ dw, const float* __restrict__ bn2g,
    const float* __restrict__ bn2b, const float* __restrict__ sew1,
    const float* __restrict__ sew2, const float* __restrict__ sw,
    const float* __restrict__ g3, const float* __restrict__ b3,
    float* __restrict__ yv) {
  int b = blockIdx.x, tid = threadIdx.x;
  __shared__ float xw[1024];         // xw[i] = xw_f[i-12], zero-padded
  __shared__ float y4pre[16 * 252];  // pooled rows, stride 252
  __shared__ float dws[16 * 19], w1s[16 * 25];
  __shared__ float sws[4096];
  __shared__ float s_s[16], se_s[16], u4[4];
  __shared__ float red[256];

  for (int i = tid; i < 16 * 19; i += 256) dws[i] = dw[i];
  for (int i = tid; i < 16 * 25; i += 256) w1s[i] = w1[i];
  for (int i = tid; i < 4096; i += 256) sws[i] = sw[i];
  __syncthreads();

  const float* xb = x + (size_t)b * NCH * TLEN;
  int lane = tid & 63, wid = tid >> 6;
  for (int f = 0; f < 16; f++) {
    // phase A: xw_f[t] = sum_c dw[f,c] * x[b,c,t]
    const float* dr = &dws[f * 19];
    for (int i = tid; i < 1024; i += 256) {
      int t = i - 12;
      float v = 0.f;
      if (t >= 0 && t < TLEN) {
#pragma unroll
        for (int c = 0; c < 19; c++) v += dr[c] * xb[c * TLEN + t];
      }
      xw[i] = v;
    }
    __syncthreads();
    float g1 = bn1g[f], b1 = bn1b[f];
    float g2 = bn2g[f], b2 = bn2b[f];
    float sumdw = 0.f;
#pragma unroll
    for (int c = 0; c < 19; c++) sumdw += dr[c];
    float scale = g2 * g1, cb = g2 * b1 * sumdw + b2;
    // phase B: conv25 + bn + elu, squeeze sum, avgpool4
    const float* wr = &w1s[f * 25];
    float part = 0.f;
    for (int p = tid; p < 250; p += 256) {
      float pool = 0.f;
#pragma unroll
      for (int q = 0; q < 4; q++) {
        int t = 4 * p + q;
        float acc = 0.f;
#pragma unroll
        for (int k = 0; k < 25; k++) acc += wr[k] * xw[t + k];
        pool += eluf(scale * acc + cb);
      }
      part += pool;
      y4pre[f * 252 + p] = pool * 0.25f;
    }
    for (int off = 32; off > 0; off >>= 1) part += __shfl_down(part, off, 64);
    if (lane == 0) red[wid] = part;
    __syncthreads();
    if (tid == 0) s_s[f] = (red[0] + red[1] + red[2] + red[3]) * (1.f / 1000.f);
    __syncthreads();
  }
  // SE MLP: sigmoid(gelu(s @ se_w1) @ se_w2)
  if (tid < 4) {
    float a = 0.f;
#pragma unroll
    for (int ff = 0; ff < 16; ff++) a += s_s[ff] * sew1[ff * 4 + tid];
    u4[tid] = geluf(a);
  }
  __syncthreads();
  if (tid < 16) {
    float a = 0.f;
#pragma unroll
    for (int j = 0; j < 4; j++) a += u4[j] * sew2[j * 16 + tid];
    se_s[tid] = sigf(a);
  }
  __syncthreads();
  for (int idx = tid; idx < 4000; idx += 256) {
    int f = idx / 250, p = idx - f * 250;
    y4pre[f * 252 + p] *= se_s[f];
  }
  __syncthreads();
  // separable conv (16->16, k=16, pad 8) + bn3 + elu + mean over 251
  int fo = tid >> 4, lane16 = tid & 15;
  float g3v = g3[fo], b3v = b3[fo];
  float accsum = 0.f;
  for (int o = lane16; o < 251; o += 16) {
    float acc = 0.f;
    int klo = (o < 8) ? (8 - o) : 0;
    int khi = (258 - o < 16) ? (258 - o) : 16;
    for (int fi = 0; fi < 16; fi++) {
      const float* yr = &y4pre[fi * 252 + o - 8];
      const float* wp = &sws[fo * 256 + fi * 16];
      for (int k = klo; k < khi; k++) acc += yr[k] * wp[k];
    }
    accsum += eluf(g3v * acc + b3v);
  }
  red[tid] = accsum;
  __syncthreads();
  for (int s = 8; s > 0; s >>= 1) {
    if (lane16 < s) red[tid] += red[tid + s];
    __syncthreads();
  }
  if (lane16 == 0) yv[b * 16 + fo] = red[tid] * (1.f / 251.f);
}

// ---------------------------------------------------------------------------
// K2: multiscale conv1d (k=15/25/35) + bn + elu, sum/3, mean -> feat
// grid: NNODES blocks
// ---------------------------------------------------------------------------
__global__ __launch_bounds__(256) void k_ms(
    const float* __restrict__ x, const float* __restrict__ w0,
    const float* __restrict__ ga0, const float* __restrict__ bb0,
    const float* __restrict__ w1, const float* __restrict__ ga1,
    const float* __restrict__ bb1, const float* __restrict__ w2,
    const float* __restrict__ ga2, const float* __restrict__ bb2,
    const float* __restrict__ yv, float* __restrict__ feat) {
  int n = blockIdx.x, tid = threadIdx.x;
  __shared__ float xr[1034];  // xr[i] = x[n, i-17], zero padded
  __shared__ float w0s[240], w1s[400], w2s[560];
  __shared__ float p0[16], q0[16], p1[16], q1[16], p2[16], q2[16];
  __shared__ float redm[4][16];
  for (int i = tid; i < 1034; i += 256) {
    int t = i - 17;
    xr[i] = (t >= 0 && t < TLEN) ? x[(size_t)n * TLEN + t] : 0.f;
  }
  for (int i = tid; i < 240; i += 256) w0s[i] = w0[i];
  for (int i = tid; i < 400; i += 256) w1s[i] = w1[i];
  for (int i = tid; i < 560; i += 256) w2s[i] = w2[i];
  if (tid < 16) {
    p0[tid] = ga0[tid]; q0[tid] = bb0[tid];
    p1[tid] = ga1[tid]; q1[tid] = bb1[tid];
    p2[tid] = ga2[tid]; q2[tid] = bb2[tid];
  }
  __syncthreads();
  float zf[16];
#pragma unroll
  for (int f = 0; f < 16; f++) zf[f] = 0.f;
  for (int p = tid; p < TLEN; p += 256) {
    const float* xc = &xr[p];
#pragma unroll
    for (int f = 0; f < 16; f++) {
      float a0 = 0.f, a1 = 0.f, a2 = 0.f;
#pragma unroll
      for (int k = 0; k < 15; k++) a0 += xc[10 + k] * w0s[f * 15 + k];
#pragma unroll
      for (int k = 0; k < 25; k++) a1 += xc[5 + k] * w1s[f * 25 + k];
#pragma unroll
      for (int k = 0; k < 35; k++) a2 += xc[k] * w2s[f * 35 + k];
      float e0 = eluf(p0[f] * a0 + q0[f]);
      float e1 = eluf(p1[f] * a1 + q1[f]);
      float e2 = eluf(p2[f] * a2 + q2[f]);
      zf[f] += (e0 + e1 + e2);
    }
  }
  int lane = tid & 63, wid = tid >> 6;
#pragma unroll
  for (int f = 0; f < 16; f++) {
    float v = zf[f];
    for (int off = 32; off > 0; off >>= 1) v += __shfl_down(v, off, 64);
    if (lane == 0) redm[wid][f] = v;
  }
  __syncthreads();
  if (tid < 16) {
    float tot = redm[0][tid] + redm[1][tid] + redm[2][tid] + redm[3][tid];
    feat[(size_t)n * 32 + 16 + tid] = tot * (1.f / 3000.f);
    feat[(size_t)n * 32 + tid] = yv[(n / 19) * 16 + tid];
  }
}

// ---------------------------------------------------------------------------
// K3: GAT layer 1, per-batch block (dense 19x19 graph incl. self-loops)
// grid: B blocks
// ---------------------------------------------------------------------------
__global__ __launch_bounds__(256) void k_gat1(
    const float* __restrict__ feat, const float* __restrict__ adjw,
    const float* __restrict__ adjb, const float* __restrict__ gw,
    const float* __restrict__ gas, const float* __restrict__ gad,
    const float* __restrict__ gbias, const float* __restrict__ skw,
    const float* __restrict__ skb, const float* __restrict__ bg,
    const float* __restrict__ bb, float* __restrict__ sc_out,
    float* __restrict__ hfeat) {
  int b = blockIdx.x, tid = threadIdx.x;
  __shared__ float fb[19 * 32];
  __shared__ float h1[19 * 512];
  __shared__ float as_s[19 * 8], ad_s[19 * 8], sc_s[19];
  __shared__ float watt[19 * 8 * 19];  // [(j*8+h)*19 + i]
  for (int i = tid; i < 19 * 32; i += 256) fb[i] = feat[(size_t)b * 19 * 32 + i];
  __syncthreads();
  for (int idx = tid; idx < 19 * 512; idx += 256) {
    int i = idx >> 9, o = idx & 511;
    const float* fr = &fb[i * 32];
    float a = 0.f;
#pragma unroll
    for (int c = 0; c < 32; c++) a += fr[c] * gw[c * 512 + o];
    h1[idx] = a;
  }
  if (tid < 19) {
    float a = adjb[0];
#pragma unroll
    for (int c = 0; c < 32; c++) a += fb[tid * 32 + c] * adjw[c];
    float s = sigf(a);
    sc_s[tid] = s;
    sc_out[b * 19 + tid] = s;
  }
  __syncthreads();
  if (tid < 152) {
    int i = tid / 8, h = tid & 7;
    float a = 0.f, d2 = 0.f;
#pragma unroll
    for (int d = 0; d < 64; d++) {
      float hv = h1[i * 512 + h * 64 + d];
      a += hv * gas[h * 64 + d];
      d2 += hv * gad[h * 64 + d];
    }
    as_s[tid] = a;
    ad_s[tid] = d2;
  }
  __syncthreads();
  if (tid < 152) {
    int j = tid / 8, h = tid & 7;
    float adj_ = ad_s[j * 8 + h];
    float ev[19], m = -1e30f;
#pragma unroll
    for (int i = 0; i < 19; i++) {
      float e = lrelu(as_s[i * 8 + h] + adj_);
      ev[i] = e;
      m = fmaxf(m, e);
    }
    float den = 0.f;
#pragma unroll
    for (int i = 0; i < 19; i++) {
      ev[i] = expf(ev[i] - m);
      den += ev[i];
    }
    float inv = 1.f / (den + 1e-16f);
    float scj = sc_s[j];
#pragma unroll
    for (int i = 0; i < 19; i++)
      watt[(j * 8 + h) * 19 + i] = ev[i] * inv * sc_s[i] * scj;
  }
  __syncthreads();
  for (int idx = tid; idx < 19 * 64; idx += 256) {
    int j = idx >> 6, d = idx & 63;
    float acc = 0.f;
#pragma unroll
    for (int h = 0; h < 8; h++) {
      const float* wr = &watt[(j * 8 + h) * 19];
      float a = 0.f;
#pragma unroll
      for (int i = 0; i < 19; i++) a += wr[i] * h1[i * 512 + h * 64 + d];
      acc += a;
    }
    float om = acc * 0.125f + gbias[d];
    float v = bg[d] * om + bb[d];
    float sk = skb[d];
    const float* fr = &fb[j * 32];
#pragma unroll
    for (int c = 0; c < 32; c++) sk += fr[c] * skw[c * 64 + d];
    hfeat[(size_t)(b * 19 + j) * 64 + d] = geluf(v + sk);
  }
}

// ---------------------------------------------------------------------------
// K4: GAT layer 2 + bn + gelu + batch mean pool + classifier -> out[b,2] (f32)
// grid: B blocks
// ---------------------------------------------------------------------------
__global__ __launch_bounds__(256) void k_gat2(
    const float* __restrict__ hfeat, const float* __restrict__ sc_ws,
    const float* __restrict__ gw, const float* __restrict__ gas,
    const float* __restrict__ gad, const float* __restrict__ gbias,
    const float* __restrict__ bg, const float* __restrict__ bb,
    const float* __restrict__ cw1, const float* __restrict__ cb1,
    const float* __restrict__ cw2, const float* __restrict__ cb2,
    float* __restrict__ out) {
  int b = blockIdx.x, tid = threadIdx.x;
  __shared__ float hb[19 * 64];
  __shared__ float h2[19 * 512];
  __shared__ float as_s[19 * 8], ad_s[19 * 8], sc_s[19];
  __shared__ float watt[19 * 8 * 19];
  __shared__ float hout[19 * 64];
  __shared__ float gpool[64], u_s[64];
  for (int i = tid; i < 19 * 64; i += 256) hb[i] = hfeat[(size_t)b * 19 * 64 + i];
  if (tid < 19) sc_s[tid] = sc_ws[b * 19 + tid];
  __syncthreads();
  for (int idx = tid; idx < 19 * 512; idx += 256) {
    int i = idx >> 9, o = idx & 511;
    const float* hr = &hb[i * 64];
    float a = 0.f;
#pragma unroll
    for (int c = 0; c < 64; c++) a += hr[c] * gw[c * 512 + o];
    h2[idx] = a;
  }
  __syncthreads();
  if (tid < 152) {
    int i = tid / 8, h = tid & 7;
    float a = 0.f, d2 = 0.f;
#pragma unroll
    for (int d = 0; d < 64; d++) {
      float hv = h2[i * 512 + h * 64 + d];
      a += hv * gas[h * 64 + d];
      d2 += hv * gad[h * 64 + d];
    }
    as_s[tid] = a;
    ad_s[tid] = d2;
  }
  __syncthreads();
  if (tid < 152) {
    int j = tid / 8, h = tid & 7;
    float adj_ = ad_s[j * 8 + h];
    float ev[19], m = -1e30f;
#pragma unroll
    for (int i = 0; i < 19; i++) {
      float e = lrelu(as_s[i * 8 + h] + adj_);
      ev[i] = e;
      m = fmaxf(m, e);
    }
    float den = 0.f;
#pragma unroll
    for (int i = 0; i < 19; i++) {
      ev[i] = expf(ev[i] - m);
      den += ev[i];
    }
    float inv = 1.f / (den + 1e-16f);
    float scj = sc_s[j];
#pragma unroll
    for (int i = 0; i < 19; i++)
      watt[(j * 8 + h) * 19 + i] = ev[i] * inv * sc_s[i] * scj;
  }
  __syncthreads();
  for (int idx = tid; idx < 19 * 64; idx += 256) {
    int j = idx >> 6, d = idx & 63;
    float acc = 0.f;
#pragma unroll
    for (int h = 0; h < 8; h++) {
      const float* wr = &watt[(j * 8 + h) * 19];
      float a = 0.f;
#pragma unroll
      for (int i = 0; i < 19; i++) a += wr[i] * h2[i * 512 + h * 64 + d];
      acc += a;
    }
    float om = acc * 0.125f + gbias[d];
    float v = bg[d] * om + bb[d] + om;
    hout[idx] = geluf(v);
  }
  __syncthreads();
  if (tid < 64) {
    float a = 0.f;
#pragma unroll
    for (int j = 0; j < 19; j++) a += hout[j * 64 + tid];
    gpool[tid] = a * (1.f / 19.f);
  }
  __syncthreads();
  if (tid < 64) {
    float a = cb1[tid];
#pragma unroll
    for (int d = 0; d < 64; d++) a += gpool[d] * cw1[d * 64 + tid];
    u_s[tid] = geluf(a);
  }
  __syncthreads();
  if (tid < 2) {
    float a = cb2[tid];
#pragma unroll
    for (int e = 0; e < 64; e++) a += u_s[e] * cw2[e * 2 + tid];
    out[b * 2 + tid] = a;  // f32 output, matching reference output dtype
  }
}

// ---------------------------------------------------------------------------
extern "C" void kernel_launch(void* const* d_in, const int* in_sizes, int n_in,
                              void* d_out, int out_size, void* d_ws,
                              size_t ws_size, hipStream_t stream) {
  (void)in_sizes; (void)n_in; (void)out_size; (void)ws_size;
  const float* x = (const float*)d_in[0];
  const float* conv1_w = (const float*)d_in[1];
  const float* bn1_g = (const float*)d_in[2];
  const float* bn1_b = (const float*)d_in[3];
  const float* depth_w = (const float*)d_in[4];
  const float* bn2_g = (const float*)d_in[5];
  const float* bn2_b = (const float*)d_in[6];
  const float* se_w1 = (const float*)d_in[7];
  const float* se_w2 = (const float*)d_in[8];
  const float* sep_w = (const float*)d_in[9];
  const float* bn3_g = (const float*)d_in[10];
  const float* bn3_b = (const float*)d_in[11];
  const float* ms_w0 = (const float*)d_in[12];
  const float* ms_g0 = (const float*)d_in[13];
  const float* ms_b0 = (const float*)d_in[14];
  const float* ms_w1 = (const float*)d_in[15];
  const float* ms_g1 = (const float*)d_in[16];
  const float* ms_b1 = (const float*)d_in[17];
  const float* ms_w2 = (const float*)d_in[18];
  const float* ms_g2 = (const float*)d_in[19];
  const float* ms_b2 = (const float*)d_in[20];
  const float* adj_w = (const float*)d_in[21];
  const float* adj_b = (const float*)d_in[22];
  const float* gat1_w = (const float*)d_in[23];
  const float* gat1_as = (const float*)d_in[24];
  const float* gat1_ad = (const float*)d_in[25];
  const float* gat1_bias = (const float*)d_in[26];
  const float* skip1_w = (const float*)d_in[27];
  const float* skip1_b = (const float*)d_in[28];
  const float* bng1_g = (const float*)d_in[29];
  const float* bng1_b = (const float*)d_in[30];
  const float* gat2_w = (const float*)d_in[31];
  const float* gat2_as = (const float*)d_in[32];
  const float* gat2_ad = (const float*)d_in[33];
  const float* gat2_bias = (const float*)d_in[34];
  const float* bng2_g = (const float*)d_in[35];
  const float* bng2_b = (const float*)d_in[36];
  const float* cls_w1 = (const float*)d_in[37];
  const float* cls_b1 = (const float*)d_in[38];
  const float* cls_w2 = (const float*)d_in[39];
  const float* cls_b2 = (const float*)d_in[40];
  // d_in[41] edge_index / d_in[42] batch_idx: fixed dense structure, unused

  float* ws = (float*)d_ws;
  float* yv = ws;               // 2,048
  float* feat = ws + 2048;      // 77,824
  float* scw = ws + 79872;      // 2,432
  float* hfeat = ws + 82304;    // 155,648  -> total ~0.95 MB

  hipLaunchKernelGGL(k_front, dim3(BATCH), dim3(256), 0, stream,
                     x, conv1_w, bn1_g, bn1_b, depth_w, bn2_g, bn2_b,
                     se_w1, se_w2, sep_w, bn3_g, bn3_b, yv);
  hipLaunchKernelGGL(k_ms, dim3(NNODES), dim3(256), 0, stream,
                     x, ms_w0, ms_g0, ms_b0, ms_w1, ms_g1, ms_b1, ms_w2,
                     ms_g2, ms_b2, yv, feat);
  hipLaunchKernelGGL(k_gat1, dim3(BATCH), dim3(256), 0, stream,
                     feat, adj_w, adj_b, gat1_w, gat1_as, gat1_ad, gat1_bias,
                     skip1_w, skip1_b, bng1_g, bng1_b, scw, hfeat);
  hipLaunchKernelGGL(k_gat2, dim3(BATCH), dim3(256), 0, stream,
                     hfeat, scw, gat2_w, gat2_as, gat2_ad, gat2_bias, bng2_g,
                     bng2_b, cls_w1, cls_b1, cls_w2, cls_b2, (float*)d_out);
}

// Round 5
// 565.946 us; speedup vs baseline: 6.7528x; 6.7528x over previous
//
#include <hip/hip_runtime.h>
#include <hip/hip_bf16.h>
#include <math.h>

#define BATCH 128
#define NCH 19
#define TLEN 1000
#define NNODES (BATCH * NCH)

__device__ __forceinline__ float eluf(float x) { return x > 0.f ? x : expm1f(x); }
__device__ __forceinline__ float geluf(float x) { return 0.5f * x * (1.f + erff(x * 0.70710678118654752f)); }
__device__ __forceinline__ float sigf(float x) { return 1.f / (1.f + expf(-x)); }
__device__ __forceinline__ float lrelu(float x) { return x > 0.f ? x : 0.2f * x; }

// ---------------------------------------------------------------------------
// K1: full EEGNet frontend for one batch element, all intermediates in LDS.
// grid: B blocks, 256 thr   (unchanged from round 4)
// ---------------------------------------------------------------------------
__global__ __launch_bounds__(256) void k_front(
    const float* __restrict__ x, const float* __restrict__ w1,
    const float* __restrict__ bn1g, const float* __restrict__ bn1b,
    const float* __restrict__ dw, const float* __restrict__ bn2g,
    const float* __restrict__ bn2b, const float* __restrict__ sew1,
    const float* __restrict__ sew2, const float* __restrict__ sw,
    const float* __restrict__ g3, const float* __restrict__ b3,
    float* __restrict__ yv) {
  int b = blockIdx.x, tid = threadIdx.x;
  __shared__ float xw[1024];         // xw[i] = xw_f[i-12], zero-padded
  __shared__ float y4pre[16 * 252];  // pooled rows, stride 252
  __shared__ float dws[16 * 19], w1s[16 * 25];
  __shared__ float sws[4096];
  __shared__ float s_s[16], se_s[16], u4[4];
  __shared__ float red[256];

  for (int i = tid; i < 16 * 19; i += 256) dws[i] = dw[i];
  for (int i = tid; i < 16 * 25; i += 256) w1s[i] = w1[i];
  for (int i = tid; i < 4096; i += 256) sws[i] = sw[i];
  __syncthreads();

  const float* xb = x + (size_t)b * NCH * TLEN;
  int lane = tid & 63, wid = tid >> 6;
  for (int f = 0; f < 16; f++) {
    const float* dr = &dws[f * 19];
    for (int i = tid; i < 1024; i += 256) {
      int t = i - 12;
      float v = 0.f;
      if (t >= 0 && t < TLEN) {
#pragma unroll
        for (int c = 0; c < 19; c++) v += dr[c] * xb[c * TLEN + t];
      }
      xw[i] = v;
    }
    __syncthreads();
    float g1 = bn1g[f], b1 = bn1b[f];
    float g2 = bn2g[f], b2 = bn2b[f];
    float sumdw = 0.f;
#pragma unroll
    for (int c = 0; c < 19; c++) sumdw += dr[c];
    float scale = g2 * g1, cb = g2 * b1 * sumdw + b2;
    const float* wr = &w1s[f * 25];
    float part = 0.f;
    for (int p = tid; p < 250; p += 256) {
      float pool = 0.f;
#pragma unroll
      for (int q = 0; q < 4; q++) {
        int t = 4 * p + q;
        float acc = 0.f;
#pragma unroll
        for (int k = 0; k < 25; k++) acc += wr[k] * xw[t + k];
        pool += eluf(scale * acc + cb);
      }
      part += pool;
      y4pre[f * 252 + p] = pool * 0.25f;
    }
    for (int off = 32; off > 0; off >>= 1) part += __shfl_down(part, off, 64);
    if (lane == 0) red[wid] = part;
    __syncthreads();
    if (tid == 0) s_s[f] = (red[0] + red[1] + red[2] + red[3]) * (1.f / 1000.f);
    __syncthreads();
  }
  if (tid < 4) {
    float a = 0.f;
#pragma unroll
    for (int ff = 0; ff < 16; ff++) a += s_s[ff] * sew1[ff * 4 + tid];
    u4[tid] = geluf(a);
  }
  __syncthreads();
  if (tid < 16) {
    float a = 0.f;
#pragma unroll
    for (int j = 0; j < 4; j++) a += u4[j] * sew2[j * 16 + tid];
    se_s[tid] = sigf(a);
  }
  __syncthreads();
  for (int idx = tid; idx < 4000; idx += 256) {
    int f = idx / 250, p = idx - f * 250;
    y4pre[f * 252 + p] *= se_s[f];
  }
  __syncthreads();
  int fo = tid >> 4, lane16 = tid & 15;
  float g3v = g3[fo], b3v = b3[fo];
  float accsum = 0.f;
  for (int o = lane16; o < 251; o += 16) {
    float acc = 0.f;
    int klo = (o < 8) ? (8 - o) : 0;
    int khi = (258 - o < 16) ? (258 - o) : 16;
    for (int fi = 0; fi < 16; fi++) {
      const float* yr = &y4pre[fi * 252 + o - 8];
      const float* wp = &sws[fo * 256 + fi * 16];
      for (int k = klo; k < khi; k++) acc += yr[k] * wp[k];
    }
    accsum += eluf(g3v * acc + b3v);
  }
  red[tid] = accsum;
  __syncthreads();
  for (int s = 8; s > 0; s >>= 1) {
    if (lane16 < s) red[tid] += red[tid + s];
    __syncthreads();
  }
  if (lane16 == 0) yv[b * 16 + fo] = red[tid] * (1.f / 251.f);
}

// ---------------------------------------------------------------------------
// K2 (REWRITTEN): multiscale conv1d. One filter f per thread (tid&15), its 75
// weights in REGISTERS; 16 p-planes (tid>>4) each produce 8 consecutive
// outputs per iteration from a 42-float register window of xr.
// Round-4 version spilled (VGPR=256, 6.8 GB scratch traffic, 4 ms).
// grid: NNODES blocks
// ---------------------------------------------------------------------------
#define RP 8
__global__ __launch_bounds__(256) void k_ms(
    const float* __restrict__ x, const float* __restrict__ w0,
    const float* __restrict__ ga0, const float* __restrict__ bb0,
    const float* __restrict__ w1, const float* __restrict__ ga1,
    const float* __restrict__ bb1, const float* __restrict__ w2,
    const float* __restrict__ ga2, const float* __restrict__ bb2,
    const float* __restrict__ yv, float* __restrict__ feat) {
  int n = blockIdx.x, tid = threadIdx.x;
  __shared__ float xr[1034];  // xr[i] = x[n, i-17], zero padded
  __shared__ float wst[1200]; // w0(240) | w1(400) | w2(560)
  __shared__ float red[256];
  for (int i = tid; i < 1034; i += 256) {
    int t = i - 17;
    xr[i] = (t >= 0 && t < TLEN) ? x[(size_t)n * TLEN + t] : 0.f;
  }
  for (int i = tid; i < 240; i += 256) wst[i] = w0[i];
  for (int i = tid; i < 400; i += 256) wst[240 + i] = w1[i];
  for (int i = tid; i < 560; i += 256) wst[640 + i] = w2[i];
  __syncthreads();

  int f = tid & 15, plane = tid >> 4;
  // per-thread weights in registers
  float wa[15], wb[25], wc[35];
#pragma unroll
  for (int k = 0; k < 15; k++) wa[k] = wst[f * 15 + k];
#pragma unroll
  for (int k = 0; k < 25; k++) wb[k] = wst[240 + f * 25 + k];
#pragma unroll
  for (int k = 0; k < 35; k++) wc[k] = wst[640 + f * 35 + k];
  float g0 = ga0[f], c0 = bb0[f];
  float g1 = ga1[f], c1 = bb1[f];
  float g2 = ga2[f], c2 = bb2[f];

  float z = 0.f;
  // base = plane*8 + 128*j < 1000  ->  base <= 992, so p = base+r <= 999:
  // no bounds check needed in the inner loop.
  for (int base = plane * RP; base < TLEN; base += 16 * RP) {
    float xv[34 + RP];
#pragma unroll
    for (int i = 0; i < 34 + RP; i++) xv[i] = xr[base + i];
#pragma unroll
    for (int r = 0; r < RP; r++) {
      float a0 = 0.f, a1 = 0.f, a2 = 0.f;
#pragma unroll
      for (int k = 0; k < 15; k++) a0 += xv[r + 10 + k] * wa[k];
#pragma unroll
      for (int k = 0; k < 25; k++) a1 += xv[r + 5 + k] * wb[k];
#pragma unroll
      for (int k = 0; k < 35; k++) a2 += xv[r + k] * wc[k];
      z += eluf(g0 * a0 + c0) + eluf(g1 * a1 + c1) + eluf(g2 * a2 + c2);
    }
  }
  // reduce over the 16 planes (red layout: plane*16 + f)
  red[tid] = z;
  __syncthreads();
  for (int s = 128; s >= 16; s >>= 1) {
    if (tid < s) red[tid] += red[tid + s];
    __syncthreads();
  }
  if (tid < 16) {
    feat[(size_t)n * 32 + 16 + tid] = red[tid] * (1.f / 3000.f);
    feat[(size_t)n * 32 + tid] = yv[(n / 19) * 16 + tid];
  }
}

// ---------------------------------------------------------------------------
// K3: GAT layer 1, per-batch block (dense 19x19 graph incl. self-loops)
// grid: B blocks   (unchanged)
// ---------------------------------------------------------------------------
__global__ __launch_bounds__(256) void k_gat1(
    const float* __restrict__ feat, const float* __restrict__ adjw,
    const float* __restrict__ adjb, const float* __restrict__ gw,
    const float* __restrict__ gas, const float* __restrict__ gad,
    const float* __restrict__ gbias, const float* __restrict__ skw,
    const float* __restrict__ skb, const float* __restrict__ bg,
    const float* __restrict__ bb, float* __restrict__ sc_out,
    float* __restrict__ hfeat) {
  int b = blockIdx.x, tid = threadIdx.x;
  __shared__ float fb[19 * 32];
  __shared__ float h1[19 * 512];
  __shared__ float as_s[19 * 8], ad_s[19 * 8], sc_s[19];
  __shared__ float watt[19 * 8 * 19];  // [(j*8+h)*19 + i]
  for (int i = tid; i < 19 * 32; i += 256) fb[i] = feat[(size_t)b * 19 * 32 + i];
  __syncthreads();
  for (int idx = tid; idx < 19 * 512; idx += 256) {
    int i = idx >> 9, o = idx & 511;
    const float* fr = &fb[i * 32];
    float a = 0.f;
#pragma unroll
    for (int c = 0; c < 32; c++) a += fr[c] * gw[c * 512 + o];
    h1[idx] = a;
  }
  if (tid < 19) {
    float a = adjb[0];
#pragma unroll
    for (int c = 0; c < 32; c++) a += fb[tid * 32 + c] * adjw[c];
    float s = sigf(a);
    sc_s[tid] = s;
    sc_out[b * 19 + tid] = s;
  }
  __syncthreads();
  if (tid < 152) {
    int i = tid / 8, h = tid & 7;
    float a = 0.f, d2 = 0.f;
#pragma unroll
    for (int d = 0; d < 64; d++) {
      float hv = h1[i * 512 + h * 64 + d];
      a += hv * gas[h * 64 + d];
      d2 += hv * gad[h * 64 + d];
    }
    as_s[tid] = a;
    ad_s[tid] = d2;
  }
  __syncthreads();
  if (tid < 152) {
    int j = tid / 8, h = tid & 7;
    float adj_ = ad_s[j * 8 + h];
    float ev[19], m = -1e30f;
#pragma unroll
    for (int i = 0; i < 19; i++) {
      float e = lrelu(as_s[i * 8 + h] + adj_);
      ev[i] = e;
      m = fmaxf(m, e);
    }
    float den = 0.f;
#pragma unroll
    for (int i = 0; i < 19; i++) {
      ev[i] = expf(ev[i] - m);
      den += ev[i];
    }
    float inv = 1.f / (den + 1e-16f);
    float scj = sc_s[j];
#pragma unroll
    for (int i = 0; i < 19; i++)
      watt[(j * 8 + h) * 19 + i] = ev[i] * inv * sc_s[i] * scj;
  }
  __syncthreads();
  for (int idx = tid; idx < 19 * 64; idx += 256) {
    int j = idx >> 6, d = idx & 63;
    float acc = 0.f;
#pragma unroll
    for (int h = 0; h < 8; h++) {
      const float* wr = &watt[(j * 8 + h) * 19];
      float a = 0.f;
#pragma unroll
      for (int i = 0; i < 19; i++) a += wr[i] * h1[i * 512 + h * 64 + d];
      acc += a;
    }
    float om = acc * 0.125f + gbias[d];
    float v = bg[d] * om + bb[d];
    float sk = skb[d];
    const float* fr = &fb[j * 32];
#pragma unroll
    for (int c = 0; c < 32; c++) sk += fr[c] * skw[c * 64 + d];
    hfeat[(size_t)(b * 19 + j) * 64 + d] = geluf(v + sk);
  }
}

// ---------------------------------------------------------------------------
// K4: GAT layer 2 + bn + gelu + batch mean pool + classifier -> out[b,2] (f32)
// grid: B blocks   (unchanged)
// ---------------------------------------------------------------------------
__global__ __launch_bounds__(256) void k_gat2(
    const float* __restrict__ hfeat, const float* __restrict__ sc_ws,
    const float* __restrict__ gw, const float* __restrict__ gas,
    const float* __restrict__ gad, const float* __restrict__ gbias,
    const float* __restrict__ bg, const float* __restrict__ bb,
    const float* __restrict__ cw1, const float* __restrict__ cb1,
    const float* __restrict__ cw2, const float* __restrict__ cb2,
    float* __restrict__ out) {
  int b = blockIdx.x, tid = threadIdx.x;
  __shared__ float hb[19 * 64];
  __shared__ float h2[19 * 512];
  __shared__ float as_s[19 * 8], ad_s[19 * 8], sc_s[19];
  __shared__ float watt[19 * 8 * 19];
  __shared__ float hout[19 * 64];
  __shared__ float gpool[64], u_s[64];
  for (int i = tid; i < 19 * 64; i += 256) hb[i] = hfeat[(size_t)b * 19 * 64 + i];
  if (tid < 19) sc_s[tid] = sc_ws[b * 19 + tid];
  __syncthreads();
  for (int idx = tid; idx < 19 * 512; idx += 256) {
    int i = idx >> 9, o = idx & 511;
    const float* hr = &hb[i * 64];
    float a = 0.f;
#pragma unroll
    for (int c = 0; c < 64; c++) a += hr[c] * gw[c * 512 + o];
    h2[idx] = a;
  }
  __syncthreads();
  if (tid < 152) {
    int i = tid / 8, h = tid & 7;
    float a = 0.f, d2 = 0.f;
#pragma unroll
    for (int d = 0; d < 64; d++) {
      float hv = h2[i * 512 + h * 64 + d];
      a += hv * gas[h * 64 + d];
      d2 += hv * gad[h * 64 + d];
    }
    as_s[tid] = a;
    ad_s[tid] = d2;
  }
  __syncthreads();
  if (tid < 152) {
    int j = tid / 8, h = tid & 7;
    float adj_ = ad_s[j * 8 + h];
    float ev[19], m = -1e30f;
#pragma unroll
    for (int i = 0; i < 19; i++) {
      float e = lrelu(as_s[i * 8 + h] + adj_);
      ev[i] = e;
      m = fmaxf(m, e);
    }
    float den = 0.f;
#pragma unroll
    for (int i = 0; i < 19; i++) {
      ev[i] = expf(ev[i] - m);
      den += ev[i];
    }
    float inv = 1.f / (den + 1e-16f);
    float scj = sc_s[j];
#pragma unroll
    for (int i = 0; i < 19; i++)
      watt[(j * 8 + h) * 19 + i] = ev[i] * inv * sc_s[i] * scj;
  }
  __syncthreads();
  for (int idx = tid; idx < 19 * 64; idx += 256) {
    int j = idx >> 6, d = idx & 63;
    float acc = 0.f;
#pragma unroll
    for (int h = 0; h < 8; h++) {
      const float* wr = &watt[(j * 8 + h) * 19];
      float a = 0.f;
#pragma unroll
      for (int i = 0; i < 19; i++) a += wr[i] * h2[i * 512 + h * 64 + d];
      acc += a;
    }
    float om = acc * 0.125f + gbias[d];
    float v = bg[d] * om + bb[d] + om;
    hout[idx] = geluf(v);
  }
  __syncthreads();
  if (tid < 64) {
    float a = 0.f;
#pragma unroll
    for (int j = 0; j < 19; j++) a += hout[j * 64 + tid];
    gpool[tid] = a * (1.f / 19.f);
  }
  __syncthreads();
  if (tid < 64) {
    float a = cb1[tid];
#pragma unroll
    for (int d = 0; d < 64; d++) a += gpool[d] * cw1[d * 64 + tid];
    u_s[tid] = geluf(a);
  }
  __syncthreads();
  if (tid < 2) {
    float a = cb2[tid];
#pragma unroll
    for (int e = 0; e < 64; e++) a += u_s[e] * cw2[e * 2 + tid];
    out[b * 2 + tid] = a;
  }
}

// ---------------------------------------------------------------------------
extern "C" void kernel_launch(void* const* d_in, const int* in_sizes, int n_in,
                              void* d_out, int out_size, void* d_ws,
                              size_t ws_size, hipStream_t stream) {
  (void)in_sizes; (void)n_in; (void)out_size; (void)ws_size;
  const float* x = (const float*)d_in[0];
  const float* conv1_w = (const float*)d_in[1];
  const float* bn1_g = (const float*)d_in[2];
  const float* bn1_b = (const float*)d_in[3];
  const float* depth_w = (const float*)d_in[4];
  const float* bn2_g = (const float*)d_in[5];
  const float* bn2_b = (const float*)d_in[6];
  const float* se_w1 = (const float*)d_in[7];
  const float* se_w2 = (const float*)d_in[8];
  const float* sep_w = (const float*)d_in[9];
  const float* bn3_g = (const float*)d_in[10];
  const float* bn3_b = (const float*)d_in[11];
  const float* ms_w0 = (const float*)d_in[12];
  const float* ms_g0 = (const float*)d_in[13];
  const float* ms_b0 = (const float*)d_in[14];
  const float* ms_w1 = (const float*)d_in[15];
  const float* ms_g1 = (const float*)d_in[16];
  const float* ms_b1 = (const float*)d_in[17];
  const float* ms_w2 = (const float*)d_in[18];
  const float* ms_g2 = (const float*)d_in[19];
  const float* ms_b2 = (const float*)d_in[20];
  const float* adj_w = (const float*)d_in[21];
  const float* adj_b = (const float*)d_in[22];
  const float* gat1_w = (const float*)d_in[23];
  const float* gat1_as = (const float*)d_in[24];
  const float* gat1_ad = (const float*)d_in[25];
  const float* gat1_bias = (const float*)d_in[26];
  const float* skip1_w = (const float*)d_in[27];
  const float* skip1_b = (const float*)d_in[28];
  const float* bng1_g = (const float*)d_in[29];
  const float* bng1_b = (const float*)d_in[30];
  const float* gat2_w = (const float*)d_in[31];
  const float* gat2_as = (const float*)d_in[32];
  const float* gat2_ad = (const float*)d_in[33];
  const float* gat2_bias = (const float*)d_in[34];
  const float* bng2_g = (const float*)d_in[35];
  const float* bng2_b = (const float*)d_in[36];
  const float* cls_w1 = (const float*)d_in[37];
  const float* cls_b1 = (const float*)d_in[38];
  const float* cls_w2 = (const float*)d_in[39];
  const float* cls_b2 = (const float*)d_in[40];
  // d_in[41] edge_index / d_in[42] batch_idx: fixed dense structure, unused

  float* ws = (float*)d_ws;
  float* yv = ws;               // 2,048
  float* feat = ws + 2048;      // 77,824
  float* scw = ws + 79872;      // 2,432
  float* hfeat = ws + 82304;    // 155,648  -> total ~0.95 MB

  hipLaunchKernelGGL(k_front, dim3(BATCH), dim3(256), 0, stream,
                     x, conv1_w, bn1_g, bn1_b, depth_w, bn2_g, bn2_b,
                     se_w1, se_w2, sep_w, bn3_g, bn3_b, yv);
  hipLaunchKernelGGL(k_ms, dim3(NNODES), dim3(256), 0, stream,
                     x, ms_w0, ms_g0, ms_b0, ms_w1, ms_g1, ms_b1, ms_w2,
                     ms_g2, ms_b2, yv, feat);
  hipLaunchKernelGGL(k_gat1, dim3(BATCH), dim3(256), 0, stream,
                     feat, adj_w, adj_b, gat1_w, gat1_as, gat1_ad, gat1_bias,
                     skip1_w, skip1_b, bng1_g, bng1_b, scw, hfeat);
  hipLaunchKernelGGL(k_gat2, dim3(BATCH), dim3(256), 0, stream,
                     hfeat, scw, gat2_w, gat2_as, gat2_ad, gat2_bias, bng2_g,
                     bng2_b, cls_w1, cls_b1, cls_w2, cls_b2, (float*)d_out);
}

// Round 6
// 374.405 us; speedup vs baseline: 10.2075x; 1.5116x over previous
//
#include <hip/hip_runtime.h>
#include <hip/hip_bf16.h>
#include <math.h>

#define BATCH 128
#define NCH 19
#define TLEN 1000
#define NNODES (BATCH * NCH)

__device__ __forceinline__ float eluf(float x) { return x > 0.f ? x : expm1f(x); }
__device__ __forceinline__ float geluf(float x) { return 0.5f * x * (1.f + erff(x * 0.70710678118654752f)); }
__device__ __forceinline__ float sigf(float x) { return 1.f / (1.f + expf(-x)); }
__device__ __forceinline__ float lrelu(float x) { return x > 0.f ? x : 0.2f * x; }

// ---------------------------------------------------------------------------
// K1a: frontend conv stage for one (b,f) pair.
//   xw_f[t] = sum_c dw[f,c]*x[b,c,t]; conv25+bn1*bn2+elu; avgpool4.
//   Writes pre-SE pooled row y4g[b,f,0:250] and squeeze sum ssum[b,f].
// grid: B*16 blocks, 256 thr
// ---------------------------------------------------------------------------
__global__ __launch_bounds__(256) void k_pool(
    const float* __restrict__ x, const float* __restrict__ w1,
    const float* __restrict__ bn1g, const float* __restrict__ bn1b,
    const float* __restrict__ dw, const float* __restrict__ bn2g,
    const float* __restrict__ bn2b, float* __restrict__ y4g,
    float* __restrict__ ssum) {
  int blk = blockIdx.x;
  int b = blk >> 4, f = blk & 15;
  int tid = threadIdx.x;
  __shared__ float xw[1024];  // xw[i] = xw_f[i-12], zero-padded
  __shared__ float dws[19], w1s[25];
  __shared__ float redw[4];
  if (tid < 19) dws[tid] = dw[f * 19 + tid];
  else if (tid >= 32 && tid < 57) w1s[tid - 32] = w1[f * 25 + tid - 32];
  __syncthreads();
  const float* xb = x + (size_t)b * NCH * TLEN;
  for (int i = tid; i < 1024; i += 256) {
    int t = i - 12;
    float v = 0.f;
    if (t >= 0 && t < TLEN) {
#pragma unroll
      for (int c = 0; c < 19; c++) v += dws[c] * xb[c * TLEN + t];
    }
    xw[i] = v;
  }
  __syncthreads();
  float g1 = bn1g[f], b1 = bn1b[f];
  float g2 = bn2g[f], b2 = bn2b[f];
  float sumdw = 0.f;
#pragma unroll
  for (int c = 0; c < 19; c++) sumdw += dws[c];
  float scale = g2 * g1, cb = g2 * b1 * sumdw + b2;
  float part = 0.f;
  if (tid < 250) {
    float pool = 0.f;
#pragma unroll
    for (int q = 0; q < 4; q++) {
      int t = 4 * tid + q;
      float acc = 0.f;
#pragma unroll
      for (int k = 0; k < 25; k++) acc += w1s[k] * xw[t + k];
      pool += eluf(scale * acc + cb);
    }
    part = pool;
    y4g[(size_t)(b * 16 + f) * 250 + tid] = pool * 0.25f;
  }
  int lane = tid & 63, wid = tid >> 6;
  for (int off = 32; off > 0; off >>= 1) part += __shfl_down(part, off, 64);
  if (lane == 0) redw[wid] = part;
  __syncthreads();
  if (tid == 0) ssum[b * 16 + f] = redw[0] + redw[1] + redw[2] + redw[3];
}

// ---------------------------------------------------------------------------
// K1b: SE (recomputed per block, tiny) + sep conv (k=16, pad 8) + bn3 + elu
//      + mean over 251 -> yv[b,fo]
// grid: B*16 blocks, 256 thr. LDS tile stride 268: zero-padded (no boundary
// branch) and non-power-of-2 (no bank-conflict stride).
// ---------------------------------------------------------------------------
__global__ __launch_bounds__(256) void k_sep(
    const float* __restrict__ y4g, const float* __restrict__ ssum,
    const float* __restrict__ sew1, const float* __restrict__ sew2,
    const float* __restrict__ sw, const float* __restrict__ g3,
    const float* __restrict__ b3, float* __restrict__ yv) {
  int blk = blockIdx.x;
  int b = blk >> 4, fo = blk & 15;
  int tid = threadIdx.x;
  __shared__ float yloc[16 * 268];  // [fi][j], data at j=8..257, zeros pad
  __shared__ float sws[256];        // sep weights for this fo
  __shared__ float s_s[16], se_s[16], u4[4];
  __shared__ float redw[4];
  sws[tid] = sw[fo * 256 + tid];
  if (tid < 16) s_s[tid] = ssum[b * 16 + tid] * (1.f / 1000.f);
  __syncthreads();
  if (tid < 4) {
    float a = 0.f;
#pragma unroll
    for (int ff = 0; ff < 16; ff++) a += s_s[ff] * sew1[ff * 4 + tid];
    u4[tid] = geluf(a);
  }
  __syncthreads();
  if (tid < 16) {
    float a = 0.f;
#pragma unroll
    for (int j = 0; j < 4; j++) a += u4[j] * sew2[j * 16 + tid];
    se_s[tid] = sigf(a);
  }
  __syncthreads();
#pragma unroll
  for (int fi = 0; fi < 16; fi++) {
    float sc = se_s[fi];
    const float* yr = y4g + (size_t)(b * 16 + fi) * 250;
    for (int j = tid; j < 268; j += 256) {
      float v = (j >= 8 && j < 258) ? yr[j - 8] * sc : 0.f;
      yloc[fi * 268 + j] = v;
    }
  }
  __syncthreads();
  float accsum = 0.f;
  if (tid < 251) {
    float acc = 0.f;
#pragma unroll
    for (int fi = 0; fi < 16; fi++) {
      const float* yr = &yloc[fi * 268 + tid];
      const float* wp = &sws[fi * 16];
#pragma unroll
      for (int k = 0; k < 16; k++) acc += yr[k] * wp[k];
    }
    accsum = eluf(g3[fo] * acc + b3[fo]);
  }
  int lane = tid & 63, wid = tid >> 6;
  for (int off = 32; off > 0; off >>= 1)
    accsum += __shfl_down(accsum, off, 64);
  if (lane == 0) redw[wid] = accsum;
  __syncthreads();
  if (tid == 0)
    yv[b * 16 + fo] = (redw[0] + redw[1] + redw[2] + redw[3]) * (1.f / 251.f);
}

// ---------------------------------------------------------------------------
// K2: multiscale conv1d. One filter f per thread (tid&15), weights in regs;
// 16 p-planes (tid>>4) each produce 8 outputs/iter from a register window.
// grid: NNODES blocks   (unchanged from round 5)
// ---------------------------------------------------------------------------
#define RP 8
__global__ __launch_bounds__(256) void k_ms(
    const float* __restrict__ x, const float* __restrict__ w0,
    const float* __restrict__ ga0, const float* __restrict__ bb0,
    const float* __restrict__ w1, const float* __restrict__ ga1,
    const float* __restrict__ bb1, const float* __restrict__ w2,
    const float* __restrict__ ga2, const float* __restrict__ bb2,
    const float* __restrict__ yv, float* __restrict__ feat) {
  int n = blockIdx.x, tid = threadIdx.x;
  __shared__ float xr[1034];  // xr[i] = x[n, i-17], zero padded
  __shared__ float wst[1200]; // w0(240) | w1(400) | w2(560)
  __shared__ float red[256];
  for (int i = tid; i < 1034; i += 256) {
    int t = i - 17;
    xr[i] = (t >= 0 && t < TLEN) ? x[(size_t)n * TLEN + t] : 0.f;
  }
  for (int i = tid; i < 240; i += 256) wst[i] = w0[i];
  for (int i = tid; i < 400; i += 256) wst[240 + i] = w1[i];
  for (int i = tid; i < 560; i += 256) wst[640 + i] = w2[i];
  __syncthreads();

  int f = tid & 15, plane = tid >> 4;
  float wa[15], wb[25], wc[35];
#pragma unroll
  for (int k = 0; k < 15; k++) wa[k] = wst[f * 15 + k];
#pragma unroll
  for (int k = 0; k < 25; k++) wb[k] = wst[240 + f * 25 + k];
#pragma unroll
  for (int k = 0; k < 35; k++) wc[k] = wst[640 + f * 35 + k];
  float g0 = ga0[f], c0 = bb0[f];
  float g1 = ga1[f], c1 = bb1[f];
  float g2 = ga2[f], c2 = bb2[f];

  float z = 0.f;
  for (int base = plane * RP; base < TLEN; base += 16 * RP) {
    float xv[34 + RP];
#pragma unroll
    for (int i = 0; i < 34 + RP; i++) xv[i] = xr[base + i];
#pragma unroll
    for (int r = 0; r < RP; r++) {
      float a0 = 0.f, a1 = 0.f, a2 = 0.f;
#pragma unroll
      for (int k = 0; k < 15; k++) a0 += xv[r + 10 + k] * wa[k];
#pragma unroll
      for (int k = 0; k < 25; k++) a1 += xv[r + 5 + k] * wb[k];
#pragma unroll
      for (int k = 0; k < 35; k++) a2 += xv[r + k] * wc[k];
      z += eluf(g0 * a0 + c0) + eluf(g1 * a1 + c1) + eluf(g2 * a2 + c2);
    }
  }
  red[tid] = z;
  __syncthreads();
  for (int s = 128; s >= 16; s >>= 1) {
    if (tid < s) red[tid] += red[tid + s];
    __syncthreads();
  }
  if (tid < 16) {
    feat[(size_t)n * 32 + 16 + tid] = red[tid] * (1.f / 3000.f);
    feat[(size_t)n * 32 + tid] = yv[(n / 19) * 16 + tid];
  }
}

// ---------------------------------------------------------------------------
// K3: GAT layer 1, per-batch block (dense 19x19 graph incl. self-loops)
// grid: B blocks   (unchanged)
// ---------------------------------------------------------------------------
__global__ __launch_bounds__(256) void k_gat1(
    const float* __restrict__ feat, const float* __restrict__ adjw,
    const float* __restrict__ adjb, const float* __restrict__ gw,
    const float* __restrict__ gas, const float* __restrict__ gad,
    const float* __restrict__ gbias, const float* __restrict__ skw,
    const float* __restrict__ skb, const float* __restrict__ bg,
    const float* __restrict__ bb, float* __restrict__ sc_out,
    float* __restrict__ hfeat) {
  int b = blockIdx.x, tid = threadIdx.x;
  __shared__ float fb[19 * 32];
  __shared__ float h1[19 * 512];
  __shared__ float as_s[19 * 8], ad_s[19 * 8], sc_s[19];
  __shared__ float watt[19 * 8 * 19];  // [(j*8+h)*19 + i]
  for (int i = tid; i < 19 * 32; i += 256) fb[i] = feat[(size_t)b * 19 * 32 + i];
  __syncthreads();
  for (int idx = tid; idx < 19 * 512; idx += 256) {
    int i = idx >> 9, o = idx & 511;
    const float* fr = &fb[i * 32];
    float a = 0.f;
#pragma unroll
    for (int c = 0; c < 32; c++) a += fr[c] * gw[c * 512 + o];
    h1[idx] = a;
  }
  if (tid < 19) {
    float a = adjb[0];
#pragma unroll
    for (int c = 0; c < 32; c++) a += fb[tid * 32 + c] * adjw[c];
    float s = sigf(a);
    sc_s[tid] = s;
    sc_out[b * 19 + tid] = s;
  }
  __syncthreads();
  if (tid < 152) {
    int i = tid / 8, h = tid & 7;
    float a = 0.f, d2 = 0.f;
#pragma unroll
    for (int d = 0; d < 64; d++) {
      float hv = h1[i * 512 + h * 64 + d];
      a += hv * gas[h * 64 + d];
      d2 += hv * gad[h * 64 + d];
    }
    as_s[tid] = a;
    ad_s[tid] = d2;
  }
  __syncthreads();
  if (tid < 152) {
    int j = tid / 8, h = tid & 7;
    float adj_ = ad_s[j * 8 + h];
    float ev[19], m = -1e30f;
#pragma unroll
    for (int i = 0; i < 19; i++) {
      float e = lrelu(as_s[i * 8 + h] + adj_);
      ev[i] = e;
      m = fmaxf(m, e);
    }
    float den = 0.f;
#pragma unroll
    for (int i = 0; i < 19; i++) {
      ev[i] = expf(ev[i] - m);
      den += ev[i];
    }
    float inv = 1.f / (den + 1e-16f);
    float scj = sc_s[j];
#pragma unroll
    for (int i = 0; i < 19; i++)
      watt[(j * 8 + h) * 19 + i] = ev[i] * inv * sc_s[i] * scj;
  }
  __syncthreads();
  for (int idx = tid; idx < 19 * 64; idx += 256) {
    int j = idx >> 6, d = idx & 63;
    float acc = 0.f;
#pragma unroll
    for (int h = 0; h < 8; h++) {
      const float* wr = &watt[(j * 8 + h) * 19];
      float a = 0.f;
#pragma unroll
      for (int i = 0; i < 19; i++) a += wr[i] * h1[i * 512 + h * 64 + d];
      acc += a;
    }
    float om = acc * 0.125f + gbias[d];
    float v = bg[d] * om + bb[d];
    float sk = skb[d];
    const float* fr = &fb[j * 32];
#pragma unroll
    for (int c = 0; c < 32; c++) sk += fr[c] * skw[c * 64 + d];
    hfeat[(size_t)(b * 19 + j) * 64 + d] = geluf(v + sk);
  }
}

// ---------------------------------------------------------------------------
// K4: GAT layer 2 + bn + gelu + batch mean pool + classifier -> out[b,2] (f32)
// grid: B blocks   (unchanged)
// ---------------------------------------------------------------------------
__global__ __launch_bounds__(256) void k_gat2(
    const float* __restrict__ hfeat, const float* __restrict__ sc_ws,
    const float* __restrict__ gw, const float* __restrict__ gas,
    const float* __restrict__ gad, const float* __restrict__ gbias,
    const float* __restrict__ bg, const float* __restrict__ bb,
    const float* __restrict__ cw1, const float* __restrict__ cb1,
    const float* __restrict__ cw2, const float* __restrict__ cb2,
    float* __restrict__ out) {
  int b = blockIdx.x, tid = threadIdx.x;
  __shared__ float hb[19 * 64];
  __shared__ float h2[19 * 512];
  __shared__ float as_s[19 * 8], ad_s[19 * 8], sc_s[19];
  __shared__ float watt[19 * 8 * 19];
  __shared__ float hout[19 * 64];
  __shared__ float gpool[64], u_s[64];
  for (int i = tid; i < 19 * 64; i += 256) hb[i] = hfeat[(size_t)b * 19 * 64 + i];
  if (tid < 19) sc_s[tid] = sc_ws[b * 19 + tid];
  __syncthreads();
  for (int idx = tid; idx < 19 * 512; idx += 256) {
    int i = idx >> 9, o = idx & 511;
    const float* hr = &hb[i * 64];
    float a = 0.f;
#pragma unroll
    for (int c = 0; c < 64; c++) a += hr[c] * gw[c * 512 + o];
    h2[idx] = a;
  }
  __syncthreads();
  if (tid < 152) {
    int i = tid / 8, h = tid & 7;
    float a = 0.f, d2 = 0.f;
#pragma unroll
    for (int d = 0; d < 64; d++) {
      float hv = h2[i * 512 + h * 64 + d];
      a += hv * gas[h * 64 + d];
      d2 += hv * gad[h * 64 + d];
    }
    as_s[tid] = a;
    ad_s[tid] = d2;
  }
  __syncthreads();
  if (tid < 152) {
    int j = tid / 8, h = tid & 7;
    float adj_ = ad_s[j * 8 + h];
    float ev[19], m = -1e30f;
#pragma unroll
    for (int i = 0; i < 19; i++) {
      float e = lrelu(as_s[i * 8 + h] + adj_);
      ev[i] = e;
      m = fmaxf(m, e);
    }
    float den = 0.f;
#pragma unroll
    for (int i = 0; i < 19; i++) {
      ev[i] = expf(ev[i] - m);
      den += ev[i];
    }
    float inv = 1.f / (den + 1e-16f);
    float scj = sc_s[j];
#pragma unroll
    for (int i = 0; i < 19; i++)
      watt[(j * 8 + h) * 19 + i] = ev[i] * inv * sc_s[i] * scj;
  }
  __syncthreads();
  for (int idx = tid; idx < 19 * 64; idx += 256) {
    int j = idx >> 6, d = idx & 63;
    float acc = 0.f;
#pragma unroll
    for (int h = 0; h < 8; h++) {
      const float* wr = &watt[(j * 8 + h) * 19];
      float a = 0.f;
#pragma unroll
      for (int i = 0; i < 19; i++) a += wr[i] * h2[i * 512 + h * 64 + d];
      acc += a;
    }
    float om = acc * 0.125f + gbias[d];
    float v = bg[d] * om + bb[d] + om;
    hout[idx] = geluf(v);
  }
  __syncthreads();
  if (tid < 64) {
    float a = 0.f;
#pragma unroll
    for (int j = 0; j < 19; j++) a += hout[j * 64 + tid];
    gpool[tid] = a * (1.f / 19.f);
  }
  __syncthreads();
  if (tid < 64) {
    float a = cb1[tid];
#pragma unroll
    for (int d = 0; d < 64; d++) a += gpool[d] * cw1[d * 64 + tid];
    u_s[tid] = geluf(a);
  }
  __syncthreads();
  if (tid < 2) {
    float a = cb2[tid];
#pragma unroll
    for (int e = 0; e < 64; e++) a += u_s[e] * cw2[e * 2 + tid];
    out[b * 2 + tid] = a;
  }
}

// ---------------------------------------------------------------------------
extern "C" void kernel_launch(void* const* d_in, const int* in_sizes, int n_in,
                              void* d_out, int out_size, void* d_ws,
                              size_t ws_size, hipStream_t stream) {
  (void)in_sizes; (void)n_in; (void)out_size; (void)ws_size;
  const float* x = (const float*)d_in[0];
  const float* conv1_w = (const float*)d_in[1];
  const float* bn1_g = (const float*)d_in[2];
  const float* bn1_b = (const float*)d_in[3];
  const float* depth_w = (const float*)d_in[4];
  const float* bn2_g = (const float*)d_in[5];
  const float* bn2_b = (const float*)d_in[6];
  const float* se_w1 = (const float*)d_in[7];
  const float* se_w2 = (const float*)d_in[8];
  const float* sep_w = (const float*)d_in[9];
  const float* bn3_g = (const float*)d_in[10];
  const float* bn3_b = (const float*)d_in[11];
  const float* ms_w0 = (const float*)d_in[12];
  const float* ms_g0 = (const float*)d_in[13];
  const float* ms_b0 = (const float*)d_in[14];
  const float* ms_w1 = (const float*)d_in[15];
  const float* ms_g1 = (const float*)d_in[16];
  const float* ms_b1 = (const float*)d_in[17];
  const float* ms_w2 = (const float*)d_in[18];
  const float* ms_g2 = (const float*)d_in[19];
  const float* ms_b2 = (const float*)d_in[20];
  const float* adj_w = (const float*)d_in[21];
  const float* adj_b = (const float*)d_in[22];
  const float* gat1_w = (const float*)d_in[23];
  const float* gat1_as = (const float*)d_in[24];
  const float* gat1_ad = (const float*)d_in[25];
  const float* gat1_bias = (const float*)d_in[26];
  const float* skip1_w = (const float*)d_in[27];
  const float* skip1_b = (const float*)d_in[28];
  const float* bng1_g = (const float*)d_in[29];
  const float* bng1_b = (const float*)d_in[30];
  const float* gat2_w = (const float*)d_in[31];
  const float* gat2_as = (const float*)d_in[32];
  const float* gat2_ad = (const float*)d_in[33];
  const float* gat2_bias = (const float*)d_in[34];
  const float* bng2_g = (const float*)d_in[35];
  const float* bng2_b = (const float*)d_in[36];
  const float* cls_w1 = (const float*)d_in[37];
  const float* cls_b1 = (const float*)d_in[38];
  const float* cls_w2 = (const float*)d_in[39];
  const float* cls_b2 = (const float*)d_in[40];
  // d_in[41] edge_index / d_in[42] batch_idx: fixed dense structure, unused

  float* ws = (float*)d_ws;
  float* yv = ws;                 // 2,048
  float* feat = ws + 2048;        // 77,824
  float* scw = ws + 79872;        // 2,432
  float* hfeat = ws + 82304;      // 155,648
  float* y4g = ws + 237952;       // 512,000
  float* ssum = ws + 749952;      // 2,048   -> total ~3.0 MB

  hipLaunchKernelGGL(k_pool, dim3(BATCH * 16), dim3(256), 0, stream,
                     x, conv1_w, bn1_g, bn1_b, depth_w, bn2_g, bn2_b, y4g, ssum);
  hipLaunchKernelGGL(k_sep, dim3(BATCH * 16), dim3(256), 0, stream,
                     y4g, ssum, se_w1, se_w2, sep_w, bn3_g, bn3_b, yv);
  hipLaunchKernelGGL(k_ms, dim3(NNODES), dim3(256), 0, stream,
                     x, ms_w0, ms_g0, ms_b0, ms_w1, ms_g1, ms_b1, ms_w2,
                     ms_g2, ms_b2, yv, feat);
  hipLaunchKernelGGL(k_gat1, dim3(BATCH), dim3(256), 0, stream,
                     feat, adj_w, adj_b, gat1_w, gat1_as, gat1_ad, gat1_bias,
                     skip1_w, skip1_b, bng1_g, bng1_b, scw, hfeat);
  hipLaunchKernelGGL(k_gat2, dim3(BATCH), dim3(256), 0, stream,
                     hfeat, scw, gat2_w, gat2_as, gat2_ad, gat2_bias, bng2_g,
                     bng2_b, cls_w1, cls_b1, cls_w2, cls_b2, (float*)d_out);
}